// Round 2
// baseline (454.814 us; speedup 1.0000x reference)
//
#include <hip/hip_runtime.h>

// Cumulative max along axis 0 of [64, 64, 128, 128] fp32.
// N = 64 scan steps, inner = 1,048,576 floats = 262,144 float4.
// Memory-bound: 256 MiB read + 256 MiB write -> ~85 us floor @ 6.3 TB/s.
//
// R1: explicit software pipeline (prefetch next 4 slices while consuming
// current 4) so each wave keeps ~8 loads in flight instead of ~4, plus
// nontemporal loads/stores (zero reuse; don't churn L2/L3).

#define SCAN_N   64
#define INNER4   (64 * 128 * 128 / 4)   // 262,144 float4 per slice

typedef float f4 __attribute__((ext_vector_type(4)));

__device__ __forceinline__ f4 max4(f4 a, f4 b) {
    f4 r;
    r.x = fmaxf(a.x, b.x);
    r.y = fmaxf(a.y, b.y);
    r.z = fmaxf(a.z, b.z);
    r.w = fmaxf(a.w, b.w);
    return r;
}

__global__ __launch_bounds__(256, 4) void cummax_axis0_kernel(
        const f4* __restrict__ x, f4* __restrict__ out) {
    const int i = blockIdx.x * blockDim.x + threadIdx.x;  // inner float4 idx

    const f4* xp = x + i;
    f4*       op = out + i;

    // Prefetch slices 0..3
    f4 p0 = __builtin_nontemporal_load(xp + 0 * INNER4);
    f4 p1 = __builtin_nontemporal_load(xp + 1 * INNER4);
    f4 p2 = __builtin_nontemporal_load(xp + 2 * INNER4);
    f4 p3 = __builtin_nontemporal_load(xp + 3 * INNER4);
    const f4* xn = xp + 4 * INNER4;

    f4 m;
    m.x = m.y = m.z = m.w = -__builtin_huge_valf();

    for (int n = 0; n < SCAN_N; n += 4) {
        const f4 c0 = p0, c1 = p1, c2 = p2, c3 = p3;
        // Issue next group's loads BEFORE waiting on / consuming this group.
        if (n + 4 < SCAN_N) {
            p0 = __builtin_nontemporal_load(xn + 0 * INNER4);
            p1 = __builtin_nontemporal_load(xn + 1 * INNER4);
            p2 = __builtin_nontemporal_load(xn + 2 * INNER4);
            p3 = __builtin_nontemporal_load(xn + 3 * INNER4);
            xn += 4 * INNER4;
        }
        m = max4(m, c0); __builtin_nontemporal_store(m, op + 0 * INNER4);
        m = max4(m, c1); __builtin_nontemporal_store(m, op + 1 * INNER4);
        m = max4(m, c2); __builtin_nontemporal_store(m, op + 2 * INNER4);
        m = max4(m, c3); __builtin_nontemporal_store(m, op + 3 * INNER4);
        op += 4 * INNER4;
    }
}

extern "C" void kernel_launch(void* const* d_in, const int* in_sizes, int n_in,
                              void* d_out, int out_size, void* d_ws, size_t ws_size,
                              hipStream_t stream) {
    const f4* x = (const f4*)d_in[0];
    f4* out = (f4*)d_out;

    const int threads = 256;
    const int blocks = INNER4 / threads;  // 1024 blocks -> 4 blocks/CU
    cummax_axis0_kernel<<<blocks, threads, 0, stream>>>(x, out);
}